// Round 1
// baseline (1431.513 us; speedup 1.0000x reference)
//
#include <hip/hip_runtime.h>
#include <math.h>

#define DFEAT 128

// emb2[i] = 2 * elu(x[i] * w[i % D])   (the factor 2 folds the edge-type mask sum)
__global__ void elu_premul_kernel(const float* __restrict__ x,
                                  const float* __restrict__ w,
                                  float* __restrict__ emb2, int total4) {
    int idx = blockIdx.x * blockDim.x + threadIdx.x;   // float4 index
    if (idx >= total4) return;
    float4 xv = ((const float4*)x)[idx];
    float4 wv = ((const float4*)w)[idx & (DFEAT / 4 - 1)];
    float4 r;
    float a;
    a = xv.x * wv.x; r.x = 2.0f * (a > 0.0f ? a : (__expf(a) - 1.0f));
    a = xv.y * wv.y; r.y = 2.0f * (a > 0.0f ? a : (__expf(a) - 1.0f));
    a = xv.z * wv.z; r.z = 2.0f * (a > 0.0f ? a : (__expf(a) - 1.0f));
    a = xv.w * wv.w; r.w = 2.0f * (a > 0.0f ? a : (__expf(a) - 1.0f));
    ((float4*)emb2)[idx] = r;
}

// 32 lanes per edge; each lane handles a float4 column chunk.
__global__ void scatter_kernel(const float* __restrict__ emb2,
                               const int* __restrict__ src,
                               const int* __restrict__ dst,
                               float* __restrict__ out, int E) {
    int t = blockIdx.x * blockDim.x + threadIdx.x;
    int edge = t >> 5;
    int lane = t & 31;
    if (edge >= E) return;
    int s = src[edge];
    int d = dst[edge];
    float4 v = ((const float4*)(emb2 + (size_t)s * DFEAT))[lane];
    float* op = out + (size_t)d * DFEAT + lane * 4;
    unsafeAtomicAdd(op + 0, v.x);
    unsafeAtomicAdd(op + 1, v.y);
    unsafeAtomicAdd(op + 2, v.z);
    unsafeAtomicAdd(op + 3, v.w);
}

// Fallback if ws too small: fuse elu into the gather (recomputes per edge).
__global__ void scatter_fused_kernel(const float* __restrict__ x,
                                     const float* __restrict__ w,
                                     const int* __restrict__ src,
                                     const int* __restrict__ dst,
                                     float* __restrict__ out, int E) {
    int t = blockIdx.x * blockDim.x + threadIdx.x;
    int edge = t >> 5;
    int lane = t & 31;
    if (edge >= E) return;
    int s = src[edge];
    int d = dst[edge];
    float4 xv = ((const float4*)(x + (size_t)s * DFEAT))[lane];
    float4 wv = ((const float4*)w)[lane];
    float4 v;
    float a;
    a = xv.x * wv.x; v.x = 2.0f * (a > 0.0f ? a : (__expf(a) - 1.0f));
    a = xv.y * wv.y; v.y = 2.0f * (a > 0.0f ? a : (__expf(a) - 1.0f));
    a = xv.z * wv.z; v.z = 2.0f * (a > 0.0f ? a : (__expf(a) - 1.0f));
    a = xv.w * wv.w; v.w = 2.0f * (a > 0.0f ? a : (__expf(a) - 1.0f));
    float* op = out + (size_t)d * DFEAT + lane * 4;
    unsafeAtomicAdd(op + 0, v.x);
    unsafeAtomicAdd(op + 1, v.y);
    unsafeAtomicAdd(op + 2, v.z);
    unsafeAtomicAdd(op + 3, v.w);
}

extern "C" void kernel_launch(void* const* d_in, const int* in_sizes, int n_in,
                              void* d_out, int out_size, void* d_ws, size_t ws_size,
                              hipStream_t stream) {
    const float* x   = (const float*)d_in[0];   // graph_embedding [N, 128]
    const float* w   = (const float*)d_in[1];   // weight [1, 128]
    const int*   src = (const int*)d_in[3];     // src [E]
    const int*   dst = (const int*)d_in[4];     // dst [E]
    float* out = (float*)d_out;

    const int ND = in_sizes[0];          // N * 128
    const int E  = in_sizes[2];          // 800000

    // out is poisoned to 0xAA before every call — zero it (async, capture-safe).
    hipMemsetAsync(d_out, 0, (size_t)out_size * sizeof(float), stream);

    const size_t emb_bytes = (size_t)ND * sizeof(float);
    if (ws_size >= emb_bytes) {
        float* emb2 = (float*)d_ws;
        int total4 = ND / 4;
        elu_premul_kernel<<<(total4 + 255) / 256, 256, 0, stream>>>(x, w, emb2, total4);
        long long threads = (long long)E * 32;
        scatter_kernel<<<(int)((threads + 255) / 256), 256, 0, stream>>>(emb2, src, dst, out, E);
    } else {
        long long threads = (long long)E * 32;
        scatter_fused_kernel<<<(int)((threads + 255) / 256), 256, 0, stream>>>(x, w, src, dst, out, E);
    }
}

// Round 2
// 207.359 us; speedup vs baseline: 6.9036x; 6.9036x over previous
//
#include <hip/hip_runtime.h>
#include <math.h>

#define DFEAT 128
#define CAP 64          // slots per destination node (avg degree = 16; P(deg>64) ~ 1e-22)
#define OVF_CAP 65536   // overflow edge list capacity (never used in practice)

// emb2[i] = 2 * elu(x[i] * w[i % D])   (factor 2 folds the edge-type mask sum)
__global__ void elu_premul_kernel(const float* __restrict__ x,
                                  const float* __restrict__ w,
                                  float* __restrict__ emb2, int total4) {
    int idx = blockIdx.x * blockDim.x + threadIdx.x;   // float4 index
    if (idx >= total4) return;
    float4 xv = ((const float4*)x)[idx];
    float4 wv = ((const float4*)w)[idx & (DFEAT / 4 - 1)];
    float4 r;
    float a;
    a = xv.x * wv.x; r.x = 2.0f * (a > 0.0f ? a : (__expf(a) - 1.0f));
    a = xv.y * wv.y; r.y = 2.0f * (a > 0.0f ? a : (__expf(a) - 1.0f));
    a = xv.z * wv.z; r.z = 2.0f * (a > 0.0f ? a : (__expf(a) - 1.0f));
    a = xv.w * wv.w; r.w = 2.0f * (a > 0.0f ? a : (__expf(a) - 1.0f));
    ((float4*)emb2)[idx] = r;
}

// Bin edges by dst: counts[d] via int atomics, src ids into fixed-size slots.
__global__ void bin_edges_kernel(const int* __restrict__ src,
                                 const int* __restrict__ dst, int E,
                                 int* __restrict__ counts,
                                 int* __restrict__ slots,
                                 int* __restrict__ ovf_cnt,
                                 int* __restrict__ ovf) {
    int e = blockIdx.x * blockDim.x + threadIdx.x;
    if (e >= E) return;
    int s = src[e];
    int d = dst[e];
    int c = atomicAdd(&counts[d], 1);
    if (c < CAP) {
        slots[(size_t)d * CAP + c] = s;
    } else {
        int p = atomicAdd(ovf_cnt, 1);
        if (p < OVF_CAP) { ovf[2 * p] = s; ovf[2 * p + 1] = d; }
    }
}

// One wave (64 lanes) per destination node; lane holds float2 (2 cols).
// Gathers source rows from emb2 (L2/L3-resident), accumulates in registers,
// writes the output row exactly once. No fp32 atomics.
__global__ void gather_accum_kernel(const float* __restrict__ emb2,
                                    const int* __restrict__ counts,
                                    const int* __restrict__ slots,
                                    float* __restrict__ out, int N) {
    int wave = (blockIdx.x * blockDim.x + threadIdx.x) >> 6;
    int lane = threadIdx.x & 63;
    if (wave >= N) return;
    int n = wave;
    int cnt = counts[n];
    if (cnt > CAP) cnt = CAP;
    const int* sl = slots + (size_t)n * CAP;
    float2 acc0 = make_float2(0.0f, 0.0f);
    float2 acc1 = make_float2(0.0f, 0.0f);
    int e = 0;
    for (; e + 1 < cnt; e += 2) {
        int s0 = sl[e];
        int s1 = sl[e + 1];
        float2 v0 = ((const float2*)(emb2 + (size_t)s0 * DFEAT))[lane];
        float2 v1 = ((const float2*)(emb2 + (size_t)s1 * DFEAT))[lane];
        acc0.x += v0.x; acc0.y += v0.y;
        acc1.x += v1.x; acc1.y += v1.y;
    }
    if (e < cnt) {
        int s0 = sl[e];
        float2 v0 = ((const float2*)(emb2 + (size_t)s0 * DFEAT))[lane];
        acc0.x += v0.x; acc0.y += v0.y;
    }
    acc0.x += acc1.x; acc0.y += acc1.y;
    ((float2*)(out + (size_t)n * DFEAT))[lane] = acc0;
}

// Overflow edges (practically never): 32 lanes/edge, atomic adds, grid-stride.
__global__ void ovf_scatter_kernel(const float* __restrict__ emb2,
                                   const int* __restrict__ ovf_cnt_p,
                                   const int* __restrict__ ovf,
                                   float* __restrict__ out) {
    int cnt = *ovf_cnt_p;
    if (cnt > OVF_CAP) cnt = OVF_CAP;
    int t = blockIdx.x * blockDim.x + threadIdx.x;
    int lane = t & 31;
    int stride = (gridDim.x * blockDim.x) >> 5;
    for (int idx = t >> 5; idx < cnt; idx += stride) {
        int s = ovf[2 * idx];
        int d = ovf[2 * idx + 1];
        float4 v = ((const float4*)(emb2 + (size_t)s * DFEAT))[lane];
        float* op = out + (size_t)d * DFEAT + lane * 4;
        unsafeAtomicAdd(op + 0, v.x);
        unsafeAtomicAdd(op + 1, v.y);
        unsafeAtomicAdd(op + 2, v.z);
        unsafeAtomicAdd(op + 3, v.w);
    }
}

// Fallback if ws too small: fuse elu into gather, fp32 atomic scatter.
__global__ void scatter_fused_kernel(const float* __restrict__ x,
                                     const float* __restrict__ w,
                                     const int* __restrict__ src,
                                     const int* __restrict__ dst,
                                     float* __restrict__ out, int E) {
    int t = blockIdx.x * blockDim.x + threadIdx.x;
    int edge = t >> 5;
    int lane = t & 31;
    if (edge >= E) return;
    int s = src[edge];
    int d = dst[edge];
    float4 xv = ((const float4*)(x + (size_t)s * DFEAT))[lane];
    float4 wv = ((const float4*)w)[lane];
    float4 v;
    float a;
    a = xv.x * wv.x; v.x = 2.0f * (a > 0.0f ? a : (__expf(a) - 1.0f));
    a = xv.y * wv.y; v.y = 2.0f * (a > 0.0f ? a : (__expf(a) - 1.0f));
    a = xv.z * wv.z; v.z = 2.0f * (a > 0.0f ? a : (__expf(a) - 1.0f));
    a = xv.w * wv.w; v.w = 2.0f * (a > 0.0f ? a : (__expf(a) - 1.0f));
    float* op = out + (size_t)d * DFEAT + lane * 4;
    unsafeAtomicAdd(op + 0, v.x);
    unsafeAtomicAdd(op + 1, v.y);
    unsafeAtomicAdd(op + 2, v.z);
    unsafeAtomicAdd(op + 3, v.w);
}

extern "C" void kernel_launch(void* const* d_in, const int* in_sizes, int n_in,
                              void* d_out, int out_size, void* d_ws, size_t ws_size,
                              hipStream_t stream) {
    const float* x   = (const float*)d_in[0];   // graph_embedding [N, 128]
    const float* w   = (const float*)d_in[1];   // weight [1, 128]
    const int*   src = (const int*)d_in[3];     // src [E]
    const int*   dst = (const int*)d_in[4];     // dst [E]
    float* out = (float*)d_out;

    const int ND = in_sizes[0];          // N * 128
    const int N  = ND / DFEAT;           // 50000
    const int E  = in_sizes[2];          // 800000

    // ws layout (all offsets 16B-aligned)
    size_t emb_bytes    = (size_t)ND * sizeof(float);
    size_t counts_bytes = (size_t)N * sizeof(int);
    size_t slots_bytes  = (size_t)N * CAP * sizeof(int);
    size_t ovf_bytes    = 16 + (size_t)2 * OVF_CAP * sizeof(int);
    size_t total = emb_bytes + counts_bytes + slots_bytes + ovf_bytes;

    if (ws_size >= total) {
        char* p = (char*)d_ws;
        float* emb2   = (float*)p;                       p += emb_bytes;
        int*   counts = (int*)p;                         p += counts_bytes;
        int*   slots  = (int*)p;                         p += slots_bytes;
        int*   ovf_c  = (int*)p;                         p += 16;
        int*   ovf    = (int*)p;

        // zero the counters (ws is re-poisoned to 0xAA before every call)
        hipMemsetAsync(counts, 0, counts_bytes, stream);
        hipMemsetAsync(ovf_c, 0, 16, stream);

        int total4 = ND / 4;
        elu_premul_kernel<<<(total4 + 255) / 256, 256, 0, stream>>>(x, w, emb2, total4);
        bin_edges_kernel<<<(E + 255) / 256, 256, 0, stream>>>(src, dst, E, counts, slots, ovf_c, ovf);
        long long thr = (long long)N * 64;
        gather_accum_kernel<<<(int)((thr + 255) / 256), 256, 0, stream>>>(emb2, counts, slots, out, N);
        ovf_scatter_kernel<<<64, 256, 0, stream>>>(emb2, ovf_c, ovf, out);
    } else {
        hipMemsetAsync(d_out, 0, (size_t)out_size * sizeof(float), stream);
        long long threads = (long long)E * 32;
        scatter_fused_kernel<<<(int)((threads + 255) / 256), 256, 0, stream>>>(x, w, src, dst, out, E);
    }
}

// Round 3
// 167.785 us; speedup vs baseline: 8.5318x; 1.2359x over previous
//
#include <hip/hip_runtime.h>
#include <hip/hip_fp16.h>
#include <math.h>

#define DFEAT 128
typedef unsigned long long u64;
typedef unsigned int u32;
#define ENDK 0xFFFFFFFFFFFFFFFFULL

// Fused kernel, split by block range:
//  - blocks [0, eluBlocks): emb2[i] = fp16( 2 * elu(x[i] * w[i % D]) )
//  - blocks [eluBlocks, ..): linked-list binning:
//      head64[d] <- atomicExch packed(src[e], e);  next64[e] <- old (coalesced)
__global__ void fused_elu_bin_kernel(const float* __restrict__ x,
                                     const float* __restrict__ w,
                                     __half* __restrict__ emb2, int total4,
                                     const int* __restrict__ src,
                                     const int* __restrict__ dst, int E,
                                     u64* __restrict__ head,
                                     u64* __restrict__ nxt,
                                     int eluBlocks) {
    if ((int)blockIdx.x < eluBlocks) {
        int idx = blockIdx.x * blockDim.x + threadIdx.x;   // group of 4 floats
        if (idx >= total4) return;
        float4 xv = ((const float4*)x)[idx];
        float4 wv = ((const float4*)w)[idx & (DFEAT / 4 - 1)];
        float a, r0, r1, r2, r3;
        a = xv.x * wv.x; r0 = 2.0f * (a > 0.0f ? a : (__expf(a) - 1.0f));
        a = xv.y * wv.y; r1 = 2.0f * (a > 0.0f ? a : (__expf(a) - 1.0f));
        a = xv.z * wv.z; r2 = 2.0f * (a > 0.0f ? a : (__expf(a) - 1.0f));
        a = xv.w * wv.w; r3 = 2.0f * (a > 0.0f ? a : (__expf(a) - 1.0f));
        __half2 h01 = __floats2half2_rn(r0, r1);
        __half2 h23 = __floats2half2_rn(r2, r3);
        uint2 pk;
        pk.x = *(u32*)&h01;
        pk.y = *(u32*)&h23;
        ((uint2*)emb2)[idx] = pk;
    } else {
        int e = (blockIdx.x - eluBlocks) * blockDim.x + threadIdx.x;
        if (e >= E) return;
        int s = src[e];
        int d = dst[e];
        u64 packed = ((u64)(u32)s << 32) | (u32)e;
        u64 old = atomicExch(&head[d], packed);
        nxt[e] = old;                       // coalesced 8B store, streams cleanly
    }
}

// One wave per 2 destination nodes; lane holds 2 columns (fp16 pair -> fp32 acc).
// Chases both linked lists concurrently: 4 independent loads in flight/iter.
__global__ void gather_ll_kernel(const __half* __restrict__ emb2,
                                 const u64* __restrict__ head,
                                 const u64* __restrict__ nxt,
                                 float* __restrict__ out, int N) {
    int wid = (blockIdx.x * blockDim.x + threadIdx.x) >> 6;
    int lane = threadIdx.x & 63;
    int nA = wid * 2;
    int nB = nA + 1;
    if (nA >= N) return;
    bool hasB = (nB < N);
    u64 curA = head[nA];
    u64 curB = hasB ? head[nB] : ENDK;
    float2 accA = make_float2(0.0f, 0.0f);
    float2 accB = make_float2(0.0f, 0.0f);
    while (curA != ENDK || curB != ENDK) {
        bool aA = (curA != ENDK);
        bool aB = (curB != ENDK);
        u64 cA = curA, cB = curB;
        u32 uA = 0, uB = 0;
        if (aA) uA = ((const u32*)(emb2 + ((size_t)(cA >> 32)) * DFEAT))[lane];
        if (aB) uB = ((const u32*)(emb2 + ((size_t)(cB >> 32)) * DFEAT))[lane];
        if (aA) curA = nxt[(u32)cA];
        if (aB) curB = nxt[(u32)cB];
        if (aA) {
            __half2 h = *(__half2*)&uA;
            float2 f = __half22float2(h);
            accA.x += f.x; accA.y += f.y;
        }
        if (aB) {
            __half2 h = *(__half2*)&uB;
            float2 f = __half22float2(h);
            accB.x += f.x; accB.y += f.y;
        }
    }
    ((float2*)(out + (size_t)nA * DFEAT))[lane] = accA;
    if (hasB) ((float2*)(out + (size_t)nB * DFEAT))[lane] = accB;
}

// Fallback if ws too small: fuse elu into gather, fp32 atomic scatter.
__global__ void scatter_fused_kernel(const float* __restrict__ x,
                                     const float* __restrict__ w,
                                     const int* __restrict__ src,
                                     const int* __restrict__ dst,
                                     float* __restrict__ out, int E) {
    int t = blockIdx.x * blockDim.x + threadIdx.x;
    int edge = t >> 5;
    int lane = t & 31;
    if (edge >= E) return;
    int s = src[edge];
    int d = dst[edge];
    float4 xv = ((const float4*)(x + (size_t)s * DFEAT))[lane];
    float4 wv = ((const float4*)w)[lane];
    float4 v;
    float a;
    a = xv.x * wv.x; v.x = 2.0f * (a > 0.0f ? a : (__expf(a) - 1.0f));
    a = xv.y * wv.y; v.y = 2.0f * (a > 0.0f ? a : (__expf(a) - 1.0f));
    a = xv.z * wv.z; v.z = 2.0f * (a > 0.0f ? a : (__expf(a) - 1.0f));
    a = xv.w * wv.w; v.w = 2.0f * (a > 0.0f ? a : (__expf(a) - 1.0f));
    float* op = out + (size_t)d * DFEAT + lane * 4;
    unsafeAtomicAdd(op + 0, v.x);
    unsafeAtomicAdd(op + 1, v.y);
    unsafeAtomicAdd(op + 2, v.z);
    unsafeAtomicAdd(op + 3, v.w);
}

extern "C" void kernel_launch(void* const* d_in, const int* in_sizes, int n_in,
                              void* d_out, int out_size, void* d_ws, size_t ws_size,
                              hipStream_t stream) {
    const float* x   = (const float*)d_in[0];   // graph_embedding [N, 128]
    const float* w   = (const float*)d_in[1];   // weight [1, 128]
    const int*   src = (const int*)d_in[3];     // src [E]
    const int*   dst = (const int*)d_in[4];     // dst [E]
    float* out = (float*)d_out;

    const int ND = in_sizes[0];          // N * 128
    const int N  = ND / DFEAT;           // 50000
    const int E  = in_sizes[2];          // 800000

    size_t emb_bytes  = ((size_t)ND * sizeof(__half) + 15) & ~(size_t)15;  // 12.8 MB
    size_t head_bytes = ((size_t)N * sizeof(u64) + 15) & ~(size_t)15;      // 400 KB
    size_t nxt_bytes  = (size_t)E * sizeof(u64);                           // 6.4 MB
    size_t total = emb_bytes + head_bytes + nxt_bytes;

    if (ws_size >= total) {
        char* p = (char*)d_ws;
        __half* emb2 = (__half*)p;  p += emb_bytes;
        u64*    head = (u64*)p;     p += head_bytes;
        u64*    nxt  = (u64*)p;

        // sentinel-fill heads (0xFF bytes == ENDK). ws is poisoned 0xAA otherwise.
        hipMemsetAsync(head, 0xFF, (size_t)N * sizeof(u64), stream);

        int total4 = ND / 4;
        int eluBlocks = (total4 + 255) / 256;
        int binBlocks = (E + 255) / 256;
        fused_elu_bin_kernel<<<eluBlocks + binBlocks, 256, 0, stream>>>(
            x, w, emb2, total4, src, dst, E, head, nxt, eluBlocks);

        long long waves = (N + 1) / 2;
        long long thr = waves * 64;
        gather_ll_kernel<<<(int)((thr + 255) / 256), 256, 0, stream>>>(
            emb2, head, nxt, out, N);
    } else {
        hipMemsetAsync(d_out, 0, (size_t)out_size * sizeof(float), stream);
        long long threads = (long long)E * 32;
        scatter_fused_kernel<<<(int)((threads + 255) / 256), 256, 0, stream>>>(x, w, src, dst, out, E);
    }
}